// Round 20
// baseline (48.119 us; speedup 1.0000x reference)
//
#include <hip/hip_runtime.h>

// ShiftGraph: B=8, C=16, H=W=256, d=5 (r=2), 24 shifts.
// Output (flat float32): edges (B, E, 2) then ws (B, E), E = 1557540.
// R20: WAVE-PRIVATE LDS, ZERO BARRIERS. Each wave stages its own
// [4ch][3row][72col] slice (3.4 KB); lanes read only own-wave slots ->
// wave-synchronous DS ordering, no __syncthreads. Waves drift freely so
// store drains overlap other waves' stage/compute (R18 was GPU-wide
// lockstep: ~10us compute + ~22us store serialized). Store code = R18.

#define HH 256
#define WW 256
#define CC 16
#define BB 8
#define HW (HH * WW)
#define EE 1557540

__global__ __launch_bounds__(256) void shiftgraph_kernel(
    const float* __restrict__ x, float* __restrict__ out) {
    __shared__ float lds[4][872];    // per-wave slice: [4ch][3row][72col]+pad
    const int bid = blockIdx.x;
    const int b = bid & 7;           // batch -> XCD
    const int h = bid >> 3;          // row
    const int tid = threadIdx.x;
    const int wv = tid >> 6;
    const int lane = tid & 63;
    const int w0 = wv << 6;
    const int w = tid;               // = w0 + lane (column)

    const float* __restrict__ xb = x + (size_t)b * (CC * HW);
    float* __restrict__ slice = lds[wv];

    // staging map: chunk = 4 channels = 864 floats = 216 float4 groups.
    // group g -> F=4g: ch=F/216, row=(F%216)/72, colofs=(F%216)%72.
    // src col = w0-4+colofs (group-aligned clamp; garbage slots guarded).
    const float* src[4];
    int dst[4];
    bool act[4];
#pragma unroll
    for (int inst = 0; inst < 4; ++inst) {
        const int g = lane + inst * 64;
        act[inst] = (g < 216);
        const int gg = act[inst] ? g : 215;
        const int F = gg * 4;
        const int ch  = F / 216;
        const int rem = F - ch * 216;
        const int row = rem / 72;
        const int colofs = rem - row * 72;
        int c0 = w0 - 4 + colofs;
        c0 = c0 < 0 ? 0 : (c0 > 252 ? 252 : c0);
        int hr = h + row; hr = hr > HH - 1 ? HH - 1 : hr;
        src[inst] = xb + ch * HW + hr * WW + c0;
        dst[inst] = F;
    }

    // prologue: stage chunk 0
#pragma unroll
    for (int inst = 0; inst < 4; ++inst) {
        if (act[inst]) {
            *reinterpret_cast<float4*>(&slice[dst[inst]]) =
                *reinterpret_cast<const float4*>(src[inst]);
            src[inst] += 4 * HW;
        }
    }

    float acc[12];
#pragma unroll
    for (int s2 = 0; s2 < 12; ++s2) acc[s2] = 0.0f;

#pragma unroll
    for (int cc = 0; cc < 4; ++cc) {
        float4 pf[4];
        if (cc < 3) {                 // prefetch next chunk into regs
#pragma unroll
            for (int inst = 0; inst < 4; ++inst) {
                if (act[inst]) {
                    pf[inst] = *reinterpret_cast<const float4*>(src[inst]);
                    src[inst] += 4 * HW;
                }
            }
        }
#pragma unroll
        for (int c = 0; c < 4; ++c) {
            const int base = c * 216 + lane + 4;   // row 0, own column
            const float ctr = slice[base];
            float d;
            d = slice[base + 1] - ctr; acc[0] = fmaf(d, d, acc[0]);   // (0,1)
            d = slice[base + 2] - ctr; acc[1] = fmaf(d, d, acc[1]);   // (0,2)
#pragma unroll
            for (int dj = -2; dj <= 2; ++dj) {
                d = slice[base + 72 + dj] - ctr;                      // (1,dj)
                acc[4 + dj] = fmaf(d, d, acc[4 + dj]);
                d = slice[base + 144 + dj] - ctr;                     // (2,dj)
                acc[9 + dj] = fmaf(d, d, acc[9 + dj]);
            }
        }
        if (cc < 3) {                 // write next chunk (WAR safe in-wave)
#pragma unroll
            for (int inst = 0; inst < 4; ++inst) {
                if (act[inst])
                    *reinterpret_cast<float4*>(&slice[dst[inst]]) = pf[inst];
            }
        }
    }

    // ---- store burst: own + mirror (pair symmetry), plain stores ----
    float* __restrict__ edges = out;                        // (B, E, 2)
    float* __restrict__ wsp   = out + (size_t)BB * EE * 2;  // (B, E)
    const size_t bE = (size_t)b * EE;
    const int posc = h * WW + w;

    int s = 0;
#pragma unroll
    for (int di = 0; di <= 2; ++di) {
#pragma unroll
        for (int dj = (di == 0 ? 1 : -2); dj <= 2; ++dj, ++s) {
            const int i = di + 2, j = dj + 2;
            if (h + di >= HH) continue;              // wave-uniform
            const int w2 = w + dj;
            if (w2 < 0 || w2 >= WW) continue;        // <=2 edge lanes diverge

            const float scale = sqrtf((float)(di * di + dj * dj));
            const float wsv = -acc[s] * scale;

            int offF = 0, offM = 0;                  // compile-time prefixes
#pragma unroll
            for (int m = 0; m < 25; ++m) {
                const int mi = m / 5, mj = m % 5;
                if (mi == 2 && mj == 2) continue;
                const int cm = (HH - (mi < 2 ? 2 - mi : mi - 2)) *
                               (WW - (mj < 2 ? 2 - mj : mj - 2));
                if (m < i * 5 + j) offF += cm;
                if (m < (4 - i) * 5 + (4 - j)) offM += cm;
            }
            const int cww = WW - (dj < 0 ? -dj : dj);
            const int e1 = offF + h * cww + (w - (dj < 0 ? -dj : 0));
            const int e2 = offM + h * cww + (w + (dj < 0 ? dj : 0));
            const int posv = di * WW + dj;

            *reinterpret_cast<float2*>(edges + (bE + e1) * 2) =
                make_float2((float)posc, (float)(posc + posv));
            *reinterpret_cast<float2*>(edges + (bE + e2) * 2) =
                make_float2((float)(posc + posv), (float)posc);
            wsp[bE + e1] = wsv;
            wsp[bE + e2] = wsv;
        }
    }
}

extern "C" void kernel_launch(void* const* d_in, const int* in_sizes, int n_in,
                              void* d_out, int out_size, void* d_ws, size_t ws_size,
                              hipStream_t stream) {
    const float* x = (const float*)d_in[0];
    float* out = (float*)d_out;
    dim3 block(256);           // 4 waves, each owning 64 columns
    dim3 grid(HH * BB);        // one block per (row, batch)
    shiftgraph_kernel<<<grid, block, 0, stream>>>(x, out);
}

// Round 21
// 32.941 us; speedup vs baseline: 1.4608x; 1.4608x over previous
//
#include <hip/hip_runtime.h>

// ShiftGraph: B=8, C=16, H=W=256, d=5 (r=2), 24 shifts.
// Output (flat float32): edges (B, E, 2) then ws (B, E), E = 1557540.
// R21: R18 core (block-cooperative LDS staging in 4-ch chunks, pair symmetry,
// 2048x256, plain stores) + raw s_barrier/lgkmcnt barriers (NO vmcnt drain)
// + edge stores (x-independent, 100MB) interleaved 3 shifts per chunk so
// their drain overlaps stage/compute. ws stores at end.

#define HH 256
#define WW 256
#define CC 16
#define BB 8
#define HW (HH * WW)
#define EE 1557540

__global__ __launch_bounds__(256) void shiftgraph_kernel(
    const float* __restrict__ x, float* __restrict__ out) {
    __shared__ float lds[3080];     // [4ch][3rows][256cols] + pad
    const int bid = blockIdx.x;
    const int b = bid & 7;          // batch -> XCD
    const int h = bid >> 3;         // row
    const int w = threadIdx.x;      // col

    const float* __restrict__ xb = x + (size_t)b * (CC * HW);

    // staging map (R16/R18-proven): 3072 floats = [cl][row][col]
    const float* src[3];
    int dst[3];
#pragma unroll
    for (int inst = 0; inst < 3; ++inst) {
        const int flatf = inst * 1024 + w * 4;
        const int cl  = flatf / 768;
        const int rem = flatf - cl * 768;
        const int row = rem >> 8;
        const int col = rem & 255;
        int hr = h + row; hr = hr > HH - 1 ? HH - 1 : hr;  // clamp: guarded
        src[inst] = xb + cl * HW + hr * WW + col;
        dst[inst] = flatf;
    }

    float* __restrict__ edges = out;                        // (B, E, 2)
    float* __restrict__ wsp   = out + (size_t)BB * EE * 2;  // (B, E)
    const size_t bE = (size_t)b * EE;
    const int posc = h * WW + w;

    float acc[12];
#pragma unroll
    for (int s2 = 0; s2 < 12; ++s2) acc[s2] = 0.0f;

#pragma unroll
    for (int cc = 0; cc < 4; ++cc) {
        if (cc > 0) {
            // WAR: all waves done reading chunk cc-1 (reads consumed pre-arrival)
            asm volatile("" ::: "memory");
            __builtin_amdgcn_s_barrier();
            __builtin_amdgcn_sched_barrier(0);
        }
#pragma unroll
        for (int inst = 0; inst < 3; ++inst) {
            const float4 v = *reinterpret_cast<const float4*>(src[inst]);
            *reinterpret_cast<float4*>(&lds[dst[inst]]) = v;
            src[inst] += 4 * HW;
        }
        // RAW: own LDS writes complete before arrival; NO vmcnt drain
        asm volatile("s_waitcnt lgkmcnt(0)" ::: "memory");
        __builtin_amdgcn_s_barrier();
        __builtin_amdgcn_sched_barrier(0);

#pragma unroll
        for (int c = 0; c < 4; ++c) {
            const int base = c * 768 + w;   // addr = w*4 + compile-time imm
            const float ctr = lds[base];
            float d;
            d = lds[base + 1] - ctr; acc[0] = fmaf(d, d, acc[0]);   // (0,1)
            d = lds[base + 2] - ctr; acc[1] = fmaf(d, d, acc[1]);   // (0,2)
#pragma unroll
            for (int dj = -2; dj <= 2; ++dj) {
                d = lds[base + 256 + dj] - ctr;                     // (1,dj)
                acc[4 + dj] = fmaf(d, d, acc[4 + dj]);
                d = lds[base + 512 + dj] - ctr;                     // (2,dj)
                acc[9 + dj] = fmaf(d, d, acc[9 + dj]);
            }
        }

        // ---- edge stores for shifts 3cc..3cc+2 (x-independent; stores
        // stay in flight across the raw barriers) ----
        {
            int s = 0;
#pragma unroll
            for (int di = 0; di <= 2; ++di) {
#pragma unroll
                for (int dj = (di == 0 ? 1 : -2); dj <= 2; ++dj, ++s) {
                    if (s < cc * 3 || s >= cc * 3 + 3) continue;  // compile-time
                    const int i = di + 2, j = dj + 2;
                    if (h + di >= HH) continue;          // wave-uniform
                    const int w2 = w + dj;
                    if (w2 < 0 || w2 >= WW) continue;    // <=2 edge lanes

                    int offF = 0, offM = 0;              // compile-time prefixes
#pragma unroll
                    for (int m = 0; m < 25; ++m) {
                        const int mi = m / 5, mj = m % 5;
                        if (mi == 2 && mj == 2) continue;
                        const int cm = (HH - (mi < 2 ? 2 - mi : mi - 2)) *
                                       (WW - (mj < 2 ? 2 - mj : mj - 2));
                        if (m < i * 5 + j) offF += cm;
                        if (m < (4 - i) * 5 + (4 - j)) offM += cm;
                    }
                    const int cww = WW - (dj < 0 ? -dj : dj);
                    const int e1 = offF + h * cww + (w - (dj < 0 ? -dj : 0));
                    const int e2 = offM + h * cww + (w + (dj < 0 ? dj : 0));
                    const int posv = di * WW + dj;

                    *reinterpret_cast<float2*>(edges + (bE + e1) * 2) =
                        make_float2((float)posc, (float)(posc + posv));
                    *reinterpret_cast<float2*>(edges + (bE + e2) * 2) =
                        make_float2((float)(posc + posv), (float)posc);
                }
            }
        }
    }

    // ---- ws stores (own + mirror) ----
    int s = 0;
#pragma unroll
    for (int di = 0; di <= 2; ++di) {
#pragma unroll
        for (int dj = (di == 0 ? 1 : -2); dj <= 2; ++dj, ++s) {
            const int i = di + 2, j = dj + 2;
            if (h + di >= HH) continue;              // wave-uniform
            const int w2 = w + dj;
            if (w2 < 0 || w2 >= WW) continue;        // <=2 edge lanes

            const float scale = sqrtf((float)(di * di + dj * dj));
            const float wsv = -acc[s] * scale;

            int offF = 0, offM = 0;                  // compile-time prefixes
#pragma unroll
            for (int m = 0; m < 25; ++m) {
                const int mi = m / 5, mj = m % 5;
                if (mi == 2 && mj == 2) continue;
                const int cm = (HH - (mi < 2 ? 2 - mi : mi - 2)) *
                               (WW - (mj < 2 ? 2 - mj : mj - 2));
                if (m < i * 5 + j) offF += cm;
                if (m < (4 - i) * 5 + (4 - j)) offM += cm;
            }
            const int cww = WW - (dj < 0 ? -dj : dj);
            const int e1 = offF + h * cww + (w - (dj < 0 ? -dj : 0));
            const int e2 = offM + h * cww + (w + (dj < 0 ? dj : 0));

            wsp[bE + e1] = wsv;
            wsp[bE + e2] = wsv;
        }
    }
}

extern "C" void kernel_launch(void* const* d_in, const int* in_sizes, int n_in,
                              void* d_out, int out_size, void* d_ws, size_t ws_size,
                              hipStream_t stream) {
    const float* x = (const float*)d_in[0];
    float* out = (float*)d_out;
    dim3 block(WW);            // one thread per column
    dim3 grid(HH * BB);        // one block per (row, batch)
    shiftgraph_kernel<<<grid, block, 0, stream>>>(x, out);
}